// Round 12
// baseline (118.903 us; speedup 1.0000x reference)
//
#include <hip/hip_runtime.h>
#include <hip/hip_bf16.h>
#include <cstdint>

#define NB 16
#define NC 512
#define NPIX 1024
#define NHEADS 4
#define NEMB 128

typedef short bf16x8 __attribute__((ext_vector_type(8)));
typedef float f32x4 __attribute__((ext_vector_type(4)));
typedef float f32x16 __attribute__((ext_vector_type(16)));
typedef unsigned short u16x4 __attribute__((ext_vector_type(4)));
typedef unsigned short u16x8 __attribute__((ext_vector_type(8)));

__device__ __forceinline__ unsigned short f2bf(float f) {
  union { float f; unsigned u; } c; c.f = f;
  return (unsigned short)((c.u + 0x7FFFu + ((c.u >> 16) & 1u)) >> 16);
}

__device__ __forceinline__ unsigned cvtpk_bf16(float lo, float hi) {
  unsigned r;
  asm("v_cvt_pk_bf16_f32 %0, %1, %2" : "=v"(r) : "v"(lo), "v"(hi));
  return r;
}

__device__ __forceinline__ void gload_lds16(const void* g, void* l) {
  __builtin_amdgcn_global_load_lds(
      (const __attribute__((address_space(1))) unsigned int*)g,
      (__attribute__((address_space(3))) unsigned int*)l, 16, 0, 0);
}

// ---------- x: [B][C][N] f32 -> xt: [B][N][C] bf16; 4 c-tiles per block ----------
__global__ void k_prep_x(const float* __restrict__ x, unsigned short* __restrict__ xt) {
  __shared__ float tile[4][32][33];
  int bid = blockIdx.x;
  int nt = bid & 31, ct4 = (bid >> 5) & 3, b = bid >> 7;
  int n0 = nt * 32, c0 = ct4 * 128;
  int t = threadIdx.x;
  int r = t >> 3, q = t & 7;
#pragma unroll
  for (int s = 0; s < 4; s++) {
    float4 v = *(const float4*)(x + ((size_t)(b * NC + c0 + s * 32 + r)) * NPIX + n0 + q * 4);
    tile[s][r][q * 4 + 0] = v.x; tile[s][r][q * 4 + 1] = v.y;
    tile[s][r][q * 4 + 2] = v.z; tile[s][r][q * 4 + 3] = v.w;
  }
  __syncthreads();
  int cl = q * 4;
#pragma unroll
  for (int s = 0; s < 4; s++) {
    u16x4 o;
    o[0] = f2bf(tile[s][cl + 0][r]); o[1] = f2bf(tile[s][cl + 1][r]);
    o[2] = f2bf(tile[s][cl + 2][r]); o[3] = f2bf(tile[s][cl + 3][r]);
    *(u16x4*)(xt + ((size_t)(b * NPIX + n0 + r)) * NC + c0 + s * 32 + cl) = o;
  }
}

// ---------- weights f32 -> bf16, wb[3][512][512] ----------
__global__ void k_prep_w(const float* __restrict__ wq, const float* __restrict__ wk,
                         const float* __restrict__ wv, unsigned short* __restrict__ wb) {
  const float* src = blockIdx.y == 0 ? wq : (blockIdx.y == 1 ? wk : wv);
  unsigned short* dst = wb + (size_t)blockIdx.y * NC * NC;
  for (int i = blockIdx.x * 256 + threadIdx.x; i < NC * NC / 4; i += gridDim.x * 256) {
    float4 v = ((const float4*)src)[i];
    u16x4 o = { f2bf(v.x), f2bf(v.y), f2bf(v.z), f2bf(v.w) };
    ((u16x4*)dst)[i] = o;
  }
}

// ---------- QKV projection GEMM ----------
// p==0: Q -> (acc+bias)*scale*log2e, [b][hd][n][e]  (exp2-domain)
// p==1: K -> acc+bias+rh+rw, 32-row subtiles [pair][j*256B], elem(j,e) at byte
//            j*256 + ((2e) ^ ((j&15)<<4))   (16-slot swizzle; subtile = 8KB)
// p==2: V -> acc+bias, 32-col subtiles [pair][j>>5][d128][32j], elem(d,j) at byte
//            (j>>5)*8192 + d*64 + ((2*(j&31)) ^ ((d&3)<<4))
__global__ __launch_bounds__(256, 3) void k_qkv(
    const unsigned short* __restrict__ wb, const unsigned short* __restrict__ xt,
    const float* __restrict__ qb, const float* __restrict__ kb, const float* __restrict__ vb,
    const float* __restrict__ rh, const float* __restrict__ rw,
    unsigned short* __restrict__ Qs, unsigned short* __restrict__ Kn,
    unsigned short* __restrict__ Vm) {
  __shared__ unsigned short Alds[128 * 64];
  __shared__ unsigned short Blds[128 * 64];
  int bid = blockIdx.x;
  int nt = bid & 7, mt = (bid >> 3) & 3;
  int rest = bid >> 5;
  int p = rest % 3, b = rest / 3;
  int m0 = mt * 128, n0 = nt * 128;
  const unsigned short* A = wb + (size_t)p * NC * NC + (size_t)m0 * NC;
  const unsigned short* Bx = xt + (size_t)b * NPIX * NC + (size_t)n0 * NC;
  int t = threadIdx.x;
  int lane = t & 63, wid = t >> 6;
  int wm = (wid >> 1) * 64, wn = (wid & 1) * 64;
  f32x4 acc[4][4] = {};
  for (int k0 = 0; k0 < NC; k0 += 64) {
#pragma unroll
    for (int i = 0; i < 4; i++) {
      int idx = i * 256 + t;
      int row = idx >> 3, col = (idx & 7) * 8;
      gload_lds16(A + (size_t)row * NC + k0 + col, &Alds[idx * 8]);
    }
#pragma unroll
    for (int i = 0; i < 4; i++) {
      int idx = i * 256 + t;
      int row = idx >> 3, col = (idx & 7) * 8;
      gload_lds16(Bx + (size_t)row * NC + k0 + col, &Blds[idx * 8]);
    }
    __syncthreads();
#pragma unroll
    for (int ks = 0; ks < 2; ks++) {
      int kk = ks * 32 + ((lane >> 4) << 3);
      bf16x8 af[4], bfr[4];
#pragma unroll
      for (int f = 0; f < 4; f++)
        af[f] = *(const bf16x8*)&Alds[(wm + f * 16 + (lane & 15)) * 64 + kk];
#pragma unroll
      for (int f = 0; f < 4; f++)
        bfr[f] = *(const bf16x8*)&Blds[(wn + f * 16 + (lane & 15)) * 64 + kk];
#pragma unroll
      for (int fm = 0; fm < 4; fm++)
#pragma unroll
        for (int fn = 0; fn < 4; fn++)
          acc[fm][fn] = __builtin_amdgcn_mfma_f32_16x16x32_bf16(af[fm], bfr[fn], acc[fm][fn], 0, 0, 0);
    }
    __syncthreads();
  }
  // 512^-0.5 * log2(e): softmax runs in exp2 domain
  const float scale = 0.044194173824159216f * 1.4426950408889634f;
  if (p == 2) {
    char* vbase = (char*)(Vm + (size_t)(b * NHEADS + mt) * 131072);
#pragma unroll
    for (int fm = 0; fm < 4; fm++) {
#pragma unroll
      for (int r = 0; r < 4; r++) {
        int d = wm + fm * 16 + ((lane >> 4) << 2) + r;
        float bv = vb[m0 + d];
#pragma unroll
        for (int fn = 0; fn < 4; fn++) {
          int j = n0 + wn + fn * 16 + (lane & 15);
          *(unsigned short*)(vbase + (size_t)(j >> 5) * 8192 + d * 64 +
                             (((j & 31) * 2) ^ ((d & 3) << 4))) =
              f2bf(acc[fm][fn][r] + bv);
        }
      }
    }
  } else if (p == 1) {
    char* kbase = (char*)(Kn + (size_t)(b * NHEADS + mt) * 131072);
#pragma unroll
    for (int fm = 0; fm < 4; fm++) {
      int e0 = wm + fm * 16 + ((lane >> 4) << 2);
#pragma unroll
      for (int fn = 0; fn < 4; fn++) {
        int j = n0 + wn + fn * 16 + (lane & 15);
        u16x4 o;
#pragma unroll
        for (int r = 0; r < 4; r++) {
          float v = acc[fm][fn][r] + kb[m0 + e0 + r];
          v += rh[(m0 + e0 + r) * 32 + (j & 31)] + rw[(m0 + e0 + r) * 32 + (j >> 5)];
          o[r] = f2bf(v);
        }
        *(u16x4*)(kbase + (size_t)j * 256 + ((2 * e0) ^ ((j & 15) << 4))) = o;
      }
    }
  } else {
    unsigned short* dst = Qs + ((size_t)((b * NHEADS + mt) * NPIX + n0)) * NEMB;
#pragma unroll
    for (int fm = 0; fm < 4; fm++) {
      int e0 = wm + fm * 16 + ((lane >> 4) << 2);
#pragma unroll
      for (int fn = 0; fn < 4; fn++) {
        int ncol = wn + fn * 16 + (lane & 15);
        u16x4 o;
#pragma unroll
        for (int r = 0; r < 4; r++)
          o[r] = f2bf((acc[fm][fn][r] + qb[m0 + e0 + r]) * scale);
        *(u16x4*)&dst[(size_t)ncol * NEMB + e0] = o;
      }
    }
  }
}

// ---------- flash attention v11: split-KV, 8 waves (512 thr), 4 waves/SIMD ----------
// Waves 0-3: KV 0..511; waves 4-7: KV 512..1023; both cover the same 128 q-rows.
// KV tiles of 32 rows, K/V staged per-half (16KB K + 16KB V per dbuf slot = 64KB).
// No online max (r7), so half-combine is a pure ADD: half-1 writes yacc+l to LDS
// (reusing the staging buffer), one barrier, half-0 adds, scales by 1/(l0+l1), stores.
__global__ __launch_bounds__(512, 4) void k_attn(
    const unsigned short* __restrict__ Qs, const unsigned short* __restrict__ Kp,
    const unsigned short* __restrict__ Vp, float* __restrict__ out) {
  __shared__ __align__(16) char smem[68096];  // K dbuf 2x16KB @0, V dbuf @32768; reused for exchange
  int bid = blockIdx.x;
  int pair = bid & 63;  // b*4+hd; i-tiles of a pair share bid%8 -> same XCD L2
  int b = pair >> 2, hd = pair & 3;
  int i0 = (bid >> 6) * 128;
  int t = threadIdx.x, w = t >> 6, lane = t & 63;
  int l31 = lane & 31, hi5 = lane >> 5;
  int h = w >> 2, wq = w & 3;  // KV half, q-subtile
  const unsigned short* Qb = Qs + (size_t)pair * NPIX * NEMB;
  const char* Kpb = (const char*)(Kp + (size_t)pair * 131072);
  const char* Vpb = (const char*)(Vp + (size_t)pair * 131072);

  // Q B-frags: lane holds Q[q = i0+wq*32+l31][e = d8*16 + hi5*8 + 0..7]
  bf16x8 qf[8];
  {
    const unsigned short* qr = Qb + (size_t)(i0 + wq * 32 + l31) * NEMB + hi5 * 8;
#pragma unroll
    for (int d8 = 0; d8 < 8; d8++) qf[d8] = *(const bf16x8*)(qr + d8 * 16);
  }
  f32x16 yacc[4] = {};
  float l = 0.f;

  // stage tile (32 KV rows x both halves) into slot: K 16KB + V 16KB, linear copy
  // of pre-swizzled global. Global subtile for (half hh, tile) = hh*16 + tile (8KB).
  auto stage = [&](int tile, int slot) {
    char* kd = smem + slot * 16384;
    char* vd = smem + 32768 + slot * 16384;
#pragma unroll
    for (int ii = 0; ii < 2; ii++) {
      const char* ks = Kpb + (size_t)((ii * 16 + tile) * 8192) + t * 16;
      const char* vs = Vpb + (size_t)((ii * 16 + tile) * 8192) + t * 16;
      gload_lds16(ks, kd + (ii * 512 + t) * 16);
      gload_lds16(vs, vd + (ii * 512 + t) * 16);
    }
  };

  stage(0, 0);
  __syncthreads();

  const int kswz = (l31 & 15) << 4;
  const int vswz = (l31 & 3) << 4;

  for (int tt = 0; tt < 16; tt++) {
    int cur = tt & 1;
    if (tt < 15) stage(tt + 1, cur ^ 1);
    const char* Kl = smem + cur * 16384 + h * 8192;
    const char* Vl = smem + 32768 + cur * 16384 + h * 8192;
    // S^T = K Q^T : per lane 16 S-values, all for q = l31 (k rows 0..31 split by hi5)
    f32x16 sacc = (f32x16)(0.0f);
    __builtin_amdgcn_s_setprio(1);
#pragma unroll
    for (int d8 = 0; d8 < 8; d8++) {
      bf16x8 k0 = *(const bf16x8*)(Kl + l31 * 256 + ((d8 * 32 + hi5 * 16) ^ kswz));
      sacc = __builtin_amdgcn_mfma_f32_32x32x16_bf16(k0, qf[d8], sacc, 0, 0, 0);
    }
    __builtin_amdgcn_s_setprio(0);
    // P = exp2(S) (no max; bounded logits — r7 analysis); 4 independent sums
    float rs0, rs1, rs2, rs3;
    {
      float p0 = exp2f(sacc[0]), p1 = exp2f(sacc[1]), p2 = exp2f(sacc[2]), p3 = exp2f(sacc[3]);
      sacc[0] = p0; sacc[1] = p1; sacc[2] = p2; sacc[3] = p3;
      rs0 = p0; rs1 = p1; rs2 = p2; rs3 = p3;
    }
#pragma unroll
    for (int i = 4; i < 16; i += 4) {
      float p0 = exp2f(sacc[i + 0]);
      float p1 = exp2f(sacc[i + 1]);
      float p2 = exp2f(sacc[i + 2]);
      float p3 = exp2f(sacc[i + 3]);
      sacc[i + 0] = p0; sacc[i + 1] = p1; sacc[i + 2] = p2; sacc[i + 3] = p3;
      rs0 += p0; rs1 += p1; rs2 += p2; rs3 += p3;
    }
    l += (rs0 + rs1) + (rs2 + rs3);
    // pack P -> bf16 pairs; up[g] covers k = 8g + 4*hi5 + 0..3
    unsigned up[4][2];
#pragma unroll
    for (int g = 0; g < 4; g++) {
      up[g][0] = cvtpk_bf16(sacc[4 * g + 0], sacc[4 * g + 1]);
      up[g][1] = cvtpk_bf16(sacc[4 * g + 2], sacc[4 * g + 3]);
    }
    // PV per 16-k chunk: assemble B-frag via permlane32_swap (r9 algebra), then MFMA
#pragma unroll
    for (int c2 = 0; c2 < 2; c2++) {
      int gA = c2 * 2, gB = gA + 1;
      unsigned a0 = up[gA][0], b0 = up[gB][0];
      unsigned a1 = up[gA][1], b1 = up[gB][1];
      asm("v_permlane32_swap_b32 %0, %1" : "+v"(a0), "+v"(b0));
      asm("v_permlane32_swap_b32 %0, %1" : "+v"(a1), "+v"(b1));
      unsigned wd[4] = { a0, a1, b0, b1 };
      bf16x8 pf = *(bf16x8*)wd;
      __builtin_amdgcn_s_setprio(1);
#pragma unroll
      for (int ds = 0; ds < 4; ds++) {
        bf16x8 vf = *(const bf16x8*)(
            Vl + (ds * 32 + l31) * 64 + ((c2 * 32 + hi5 * 16) ^ vswz));
        yacc[ds] = __builtin_amdgcn_mfma_f32_32x32x16_bf16(vf, pf, yacc[ds], 0, 0, 0);
      }
      __builtin_amdgcn_s_setprio(0);
    }
    __syncthreads();  // all reads of cur done; vmcnt drain makes slot cur^1 ready
  }

  // ---- half-combine (pure add; no rescale needed since no online max) ----
  float l_own = l + __shfl_xor(l, 32);  // sum over this wave's full KV half
  float* ex = (float*)smem;             // [q128][132 floats] padded exchange
  float* Lw = (float*)(smem + 67584);   // [q128] l partials from half 1
  int q = wq * 32 + l31;
  if (h == 1) {
#pragma unroll
    for (int ds = 0; ds < 4; ds++)
#pragma unroll
      for (int rg = 0; rg < 4; rg++) {
        f32x4 v;
#pragma unroll
        for (int i = 0; i < 4; i++) v[i] = yacc[ds][rg * 4 + i];
        *(f32x4*)(ex + q * 132 + ds * 32 + rg * 8 + hi5 * 4) = v;
      }
    if (hi5 == 0) Lw[q] = l_own;
  }
  __syncthreads();
  if (h == 0) {
    float invl = 1.0f / (l_own + Lw[q]);
    int qg = i0 + q;
    float* orow = out + ((size_t)(b * NC + hd * NEMB + (qg >> 3))) * NPIX + (qg & 7) * NEMB;
#pragma unroll
    for (int ds = 0; ds < 4; ds++)
#pragma unroll
      for (int rg = 0; rg < 4; rg++) {
        f32x4 v2 = *(const f32x4*)(ex + q * 132 + ds * 32 + rg * 8 + hi5 * 4);
        f32x4 v;
#pragma unroll
        for (int i = 0; i < 4; i++) v[i] = (yacc[ds][rg * 4 + i] + v2[i]) * invl;
        *(f32x4*)(orow + ds * 32 + rg * 8 + hi5 * 4) = v;
      }
  }
}

extern "C" void kernel_launch(void* const* d_in, const int* in_sizes, int n_in,
                              void* d_out, int out_size, void* d_ws, size_t ws_size,
                              hipStream_t stream) {
  const float* x  = (const float*)d_in[0];
  const float* wq = (const float*)d_in[1];
  const float* qb = (const float*)d_in[2];
  const float* wk = (const float*)d_in[3];
  const float* kb = (const float*)d_in[4];
  const float* wv = (const float*)d_in[5];
  const float* vb = (const float*)d_in[6];
  const float* rh = (const float*)d_in[7];
  const float* rw = (const float*)d_in[8];
  float* out = (float*)d_out;
  char* ws = (char*)d_ws;
  // ws layout (bytes): xt 16,777,216 | wb 1,572,864 | Q 16,777,216 | K 16,777,216 | V 16,777,216
  unsigned short* xt = (unsigned short*)(ws);
  unsigned short* wb = (unsigned short*)(ws + 16777216);
  unsigned short* Q  = (unsigned short*)(ws + 18350080);
  unsigned short* K  = (unsigned short*)(ws + 35127296);
  unsigned short* V  = (unsigned short*)(ws + 51904512);
  k_prep_x<<<2048, 256, 0, stream>>>(x, xt);
  k_prep_w<<<dim3(64, 3), 256, 0, stream>>>(wq, wk, wv, wb);
  k_qkv<<<1536, 256, 0, stream>>>(wb, xt, qb, kb, vb, rh, rw, Q, K, V);
  k_attn<<<512, 512, 0, stream>>>(Q, K, V, out);
}

// Round 13
// 103.808 us; speedup vs baseline: 1.1454x; 1.1454x over previous
//
#include <hip/hip_runtime.h>
#include <hip/hip_bf16.h>
#include <cstdint>

#define NB 16
#define NC 512
#define NPIX 1024
#define NHEADS 4
#define NEMB 128

typedef short bf16x8 __attribute__((ext_vector_type(8)));
typedef float f32x4 __attribute__((ext_vector_type(4)));
typedef float f32x16 __attribute__((ext_vector_type(16)));
typedef unsigned short u16x4 __attribute__((ext_vector_type(4)));
typedef unsigned short u16x8 __attribute__((ext_vector_type(8)));

__device__ __forceinline__ unsigned short f2bf(float f) {
  union { float f; unsigned u; } c; c.f = f;
  return (unsigned short)((c.u + 0x7FFFu + ((c.u >> 16) & 1u)) >> 16);
}

__device__ __forceinline__ unsigned cvtpk_bf16(float lo, float hi) {
  unsigned r;
  asm("v_cvt_pk_bf16_f32 %0, %1, %2" : "=v"(r) : "v"(lo), "v"(hi));
  return r;
}

__device__ __forceinline__ void gload_lds16(const void* g, void* l) {
  __builtin_amdgcn_global_load_lds(
      (const __attribute__((address_space(1))) unsigned int*)g,
      (__attribute__((address_space(3))) unsigned int*)l, 16, 0, 0);
}

// ---------- x: [B][C][N] f32 -> xt: [B][N][C] bf16; 4 c-tiles per block ----------
__global__ void k_prep_x(const float* __restrict__ x, unsigned short* __restrict__ xt) {
  __shared__ float tile[4][32][33];
  int bid = blockIdx.x;
  int nt = bid & 31, ct4 = (bid >> 5) & 3, b = bid >> 7;
  int n0 = nt * 32, c0 = ct4 * 128;
  int t = threadIdx.x;
  int r = t >> 3, q = t & 7;
#pragma unroll
  for (int s = 0; s < 4; s++) {
    float4 v = *(const float4*)(x + ((size_t)(b * NC + c0 + s * 32 + r)) * NPIX + n0 + q * 4);
    tile[s][r][q * 4 + 0] = v.x; tile[s][r][q * 4 + 1] = v.y;
    tile[s][r][q * 4 + 2] = v.z; tile[s][r][q * 4 + 3] = v.w;
  }
  __syncthreads();
  int cl = q * 4;
#pragma unroll
  for (int s = 0; s < 4; s++) {
    u16x4 o;
    o[0] = f2bf(tile[s][cl + 0][r]); o[1] = f2bf(tile[s][cl + 1][r]);
    o[2] = f2bf(tile[s][cl + 2][r]); o[3] = f2bf(tile[s][cl + 3][r]);
    *(u16x4*)(xt + ((size_t)(b * NPIX + n0 + r)) * NC + c0 + s * 32 + cl) = o;
  }
}

// ---------- weights f32 -> bf16, wb[3][512][512] ----------
__global__ void k_prep_w(const float* __restrict__ wq, const float* __restrict__ wk,
                         const float* __restrict__ wv, unsigned short* __restrict__ wb) {
  const float* src = blockIdx.y == 0 ? wq : (blockIdx.y == 1 ? wk : wv);
  unsigned short* dst = wb + (size_t)blockIdx.y * NC * NC;
  for (int i = blockIdx.x * 256 + threadIdx.x; i < NC * NC / 4; i += gridDim.x * 256) {
    float4 v = ((const float4*)src)[i];
    u16x4 o = { f2bf(v.x), f2bf(v.y), f2bf(v.z), f2bf(v.w) };
    ((u16x4*)dst)[i] = o;
  }
}

// ---------- QKV projection GEMM (r9 layouts, LDS-restaged coalesced epilogue) ----------
// p==0: Q -> (acc+bias)*scale*log2e, [b][hd][n][e]  (exp2-domain)
// p==1: K -> acc+bias+rh+rw, tiles 16KB: elem(jl,e) at byte jl*256 + ((2e)^((jl&7)<<4))
// p==2: V -> acc+bias,       tiles 16KB: elem(d,jl) at byte d*128 + ((2jl)^((d&7)<<4))
// Epilogue: block's output tile is one contiguous 32KB global region for all p —
// build final-layout bytes in LDS (scatter is cheap there), then copy out as
// 8 coalesced 16B stores per thread (was: 64 scattered 2B global stores for V).
__global__ __launch_bounds__(256, 3) void k_qkv(
    const unsigned short* __restrict__ wb, const unsigned short* __restrict__ xt,
    const float* __restrict__ qb, const float* __restrict__ kb, const float* __restrict__ vb,
    const float* __restrict__ rh, const float* __restrict__ rw,
    unsigned short* __restrict__ Qs, unsigned short* __restrict__ Kn,
    unsigned short* __restrict__ Vm) {
  __shared__ __align__(16) char smem[32768];
  unsigned short* Alds = (unsigned short*)smem;
  unsigned short* Blds = (unsigned short*)(smem + 16384);
  int bid = blockIdx.x;
  int nt = bid & 7, mt = (bid >> 3) & 3;
  int rest = bid >> 5;
  int p = rest % 3, b = rest / 3;
  int m0 = mt * 128, n0 = nt * 128;
  const unsigned short* A = wb + (size_t)p * NC * NC + (size_t)m0 * NC;
  const unsigned short* Bx = xt + (size_t)b * NPIX * NC + (size_t)n0 * NC;
  int t = threadIdx.x;
  int lane = t & 63, wid = t >> 6;
  int wm = (wid >> 1) * 64, wn = (wid & 1) * 64;
  f32x4 acc[4][4] = {};
  for (int k0 = 0; k0 < NC; k0 += 64) {
#pragma unroll
    for (int i = 0; i < 4; i++) {
      int idx = i * 256 + t;
      int row = idx >> 3, col = (idx & 7) * 8;
      gload_lds16(A + (size_t)row * NC + k0 + col, &Alds[idx * 8]);
    }
#pragma unroll
    for (int i = 0; i < 4; i++) {
      int idx = i * 256 + t;
      int row = idx >> 3, col = (idx & 7) * 8;
      gload_lds16(Bx + (size_t)row * NC + k0 + col, &Blds[idx * 8]);
    }
    __syncthreads();
#pragma unroll
    for (int ks = 0; ks < 2; ks++) {
      int kk = ks * 32 + ((lane >> 4) << 3);
      bf16x8 af[4], bfr[4];
#pragma unroll
      for (int f = 0; f < 4; f++)
        af[f] = *(const bf16x8*)&Alds[(wm + f * 16 + (lane & 15)) * 64 + kk];
#pragma unroll
      for (int f = 0; f < 4; f++)
        bfr[f] = *(const bf16x8*)&Blds[(wn + f * 16 + (lane & 15)) * 64 + kk];
#pragma unroll
      for (int fm = 0; fm < 4; fm++)
#pragma unroll
        for (int fn = 0; fn < 4; fn++)
          acc[fm][fn] = __builtin_amdgcn_mfma_f32_16x16x32_bf16(af[fm], bfr[fn], acc[fm][fn], 0, 0, 0);
    }
    __syncthreads();  // last iter: all LDS reads done -> safe to reuse smem below
  }
  // 512^-0.5 * log2(e): softmax runs in exp2 domain
  const float scale = 0.044194173824159216f * 1.4426950408889634f;
  // ---- build final-layout 32KB tile in LDS ----
  if (p == 2) {
#pragma unroll
    for (int fm = 0; fm < 4; fm++) {
#pragma unroll
      for (int r = 0; r < 4; r++) {
        int d = wm + fm * 16 + ((lane >> 4) << 2) + r;
        float bv = vb[m0 + d];
#pragma unroll
        for (int fn = 0; fn < 4; fn++) {
          int jloc = wn + fn * 16 + (lane & 15);
          int sub = jloc >> 6, jl = jloc & 63;
          *(unsigned short*)(smem + sub * 16384 + d * 128 + ((2 * jl) ^ ((d & 7) << 4))) =
              f2bf(acc[fm][fn][r] + bv);
        }
      }
    }
  } else if (p == 1) {
#pragma unroll
    for (int fm = 0; fm < 4; fm++) {
      int e0 = wm + fm * 16 + ((lane >> 4) << 2);
#pragma unroll
      for (int fn = 0; fn < 4; fn++) {
        int jloc = wn + fn * 16 + (lane & 15);
        int jg = n0 + jloc;
        int sub = jloc >> 6, jl = jloc & 63;
        u16x4 o;
#pragma unroll
        for (int r = 0; r < 4; r++) {
          float v = acc[fm][fn][r] + kb[m0 + e0 + r];
          v += rh[(m0 + e0 + r) * 32 + (jg & 31)] + rw[(m0 + e0 + r) * 32 + (jg >> 5)];
          o[r] = f2bf(v);
        }
        *(u16x4*)(smem + sub * 16384 + jl * 256 + ((2 * e0) ^ ((jl & 7) << 4))) = o;
      }
    }
  } else {
#pragma unroll
    for (int fm = 0; fm < 4; fm++) {
      int e0 = wm + fm * 16 + ((lane >> 4) << 2);
#pragma unroll
      for (int fn = 0; fn < 4; fn++) {
        int ncol = wn + fn * 16 + (lane & 15);
        u16x4 o;
#pragma unroll
        for (int r = 0; r < 4; r++)
          o[r] = f2bf((acc[fm][fn][r] + qb[m0 + e0 + r]) * scale);
        *(u16x4*)(smem + ncol * 256 + 2 * e0) = o;
      }
    }
  }
  __syncthreads();
  // ---- coalesced copy-out: 8 x 16B per thread ----
  char* gdst;
  if (p == 0)
    gdst = (char*)(Qs + ((size_t)((b * NHEADS + mt) * NPIX + n0)) * NEMB);
  else if (p == 1)
    gdst = (char*)(Kn + (size_t)(b * NHEADS + mt) * 131072 + (size_t)(n0 >> 6) * 8192);
  else
    gdst = (char*)(Vm + (size_t)(b * NHEADS + mt) * 131072 + (size_t)(n0 >> 6) * 8192);
#pragma unroll
  for (int i = 0; i < 8; i++)
    *(u16x8*)(gdst + i * 4096 + t * 16) = *(const u16x8*)(smem + i * 4096 + t * 16);
}

// ---------- flash attention (r9-proven): swapped QK^T (32x32 MFMA), in-register ----------
// exp2 softmax (no max — bounded logits), permlane pack, K/V pre-swizzled ->
// linear gload_lds staging, dbuf, 1 barrier/tile. grid = 512; 4 waves x 32 q-rows.
__global__ __launch_bounds__(256, 2) void k_attn(
    const unsigned short* __restrict__ Qs, const unsigned short* __restrict__ Kp,
    const unsigned short* __restrict__ Vp, float* __restrict__ out) {
  __shared__ __align__(16) char smem[65536];  // K dbuf 2x16KB @0, V dbuf 2x16KB @32768
  int bid = blockIdx.x;
  int pair = bid & 63;                        // b*4+hd; i-tiles of a pair share bid%8 -> XCD
  int b = pair >> 2, hd = pair & 3;
  int i0 = (bid >> 6) * 128;
  int t = threadIdx.x, w = t >> 6, lane = t & 63;
  int l31 = lane & 31, hi5 = lane >> 5;
  const unsigned short* Qb = Qs + (size_t)pair * NPIX * NEMB;
  const char* Kpb = (const char*)(Kp + (size_t)pair * 131072);
  const char* Vpb = (const char*)(Vp + (size_t)pair * 131072);

  // Q B-frags: lane holds Q[q = i0+w*32+l31][d8*16 + hi5*8 + e]
  bf16x8 qf[8];
  {
    const unsigned short* qr = Qb + (size_t)(i0 + w * 32 + l31) * NEMB + hi5 * 8;
#pragma unroll
    for (int d8 = 0; d8 < 8; d8++) qf[d8] = *(const bf16x8*)(qr + d8 * 16);
  }
  f32x16 yacc[4] = {};
  float l = 0.f;

  // prologue: stage tile 0 into buf 0
#pragma unroll
  for (int r = 0; r < 4; r++) {
    gload_lds16(Kpb + r * 4096 + t * 16, smem + r * 4096 + t * 16);
    gload_lds16(Vpb + r * 4096 + t * 16, smem + 32768 + r * 4096 + t * 16);
  }
  __syncthreads();

  for (int tt = 0; tt < 16; tt++) {
    int cur = tt & 1;
    if (tt < 15) {  // prefetch next tile into other buffer (drained by barrier at loop end)
      const char* kn = Kpb + (tt + 1) * 16384;
      const char* vn = Vpb + (tt + 1) * 16384;
      char* kd = smem + (cur ^ 1) * 16384;
      char* vd = smem + 32768 + (cur ^ 1) * 16384;
#pragma unroll
      for (int r = 0; r < 4; r++) {
        gload_lds16(kn + r * 4096 + t * 16, kd + r * 4096 + t * 16);
        gload_lds16(vn + r * 4096 + t * 16, vd + r * 4096 + t * 16);
      }
    }
    const char* Kl = smem + cur * 16384;
    const char* Vl = smem + 32768 + cur * 16384;
    // S^T = K Q^T : per lane, 32 S-values for q = l31 (k rows per C-layout)
    f32x16 sacc[2] = {};
    {
      int swz = (l31 & 7) << 4;
#pragma unroll
      for (int d8 = 0; d8 < 8; d8++) {
        int colb = (d8 * 32 + hi5 * 16) ^ swz;
        bf16x8 k0 = *(const bf16x8*)(Kl + l31 * 256 + colb);
        bf16x8 k1 = *(const bf16x8*)(Kl + (32 + l31) * 256 + colb);
        __builtin_amdgcn_s_setprio(1);
        sacc[0] = __builtin_amdgcn_mfma_f32_32x32x16_bf16(k0, qf[d8], sacc[0], 0, 0, 0);
        sacc[1] = __builtin_amdgcn_mfma_f32_32x32x16_bf16(k1, qf[d8], sacc[1], 0, 0, 0);
        __builtin_amdgcn_s_setprio(0);
      }
    }
    // P = exp2(S) directly (no max; bounded logits — r7 analysis); 4 independent
    // sum accumulators; l keeps own-half partial sums (combined in epilogue).
    float rs0 = 0.f, rs1 = 0.f, rs2 = 0.f, rs3 = 0.f;
#pragma unroll
    for (int c = 0; c < 2; c++)
#pragma unroll
      for (int i = 0; i < 16; i += 4) {
        float p0 = exp2f(sacc[c][i + 0]);
        float p1 = exp2f(sacc[c][i + 1]);
        float p2 = exp2f(sacc[c][i + 2]);
        float p3 = exp2f(sacc[c][i + 3]);
        sacc[c][i + 0] = p0; sacc[c][i + 1] = p1;
        sacc[c][i + 2] = p2; sacc[c][i + 3] = p3;
        rs0 += p0; rs1 += p1; rs2 += p2; rs3 += p3;
      }
    l += (rs0 + rs1) + (rs2 + rs3);
    // pack P to bf16 pairs, assemble PV B-frags via permlane32_swap (r9 algebra)
    unsigned up[2][4][2];
#pragma unroll
    for (int c = 0; c < 2; c++)
#pragma unroll
      for (int g = 0; g < 4; g++) {
        up[c][g][0] = cvtpk_bf16(sacc[c][4 * g + 0], sacc[c][4 * g + 1]);
        up[c][g][1] = cvtpk_bf16(sacc[c][4 * g + 2], sacc[c][4 * g + 3]);
      }
    bf16x8 pf[4];
#pragma unroll
    for (int c2 = 0; c2 < 4; c2++) {
      int c = c2 >> 1, gA = (c2 & 1) * 2, gB = gA + 1;
      unsigned a0 = up[c][gA][0], b0 = up[c][gB][0];
      unsigned a1 = up[c][gA][1], b1 = up[c][gB][1];
      asm("v_permlane32_swap_b32 %0, %1" : "+v"(a0), "+v"(b0));
      asm("v_permlane32_swap_b32 %0, %1" : "+v"(a1), "+v"(b1));
      unsigned wd[4] = { a0, a1, b0, b1 };
      pf[c2] = *(bf16x8*)wd;
    }
    // y^T += V^T P^T : A = V^T from LDS (16B contig), B = pf; C cols = q (= l31)
    {
      int swz = (l31 & 7) << 4;
#pragma unroll
      for (int c2 = 0; c2 < 4; c2++) {
        int colb = (c2 * 32 + hi5 * 16) ^ swz;
        __builtin_amdgcn_s_setprio(1);
#pragma unroll
        for (int ds = 0; ds < 4; ds++) {
          bf16x8 vf = *(const bf16x8*)(Vl + (ds * 32 + l31) * 128 + colb);
          yacc[ds] = __builtin_amdgcn_mfma_f32_32x32x16_bf16(vf, pf[c2], yacc[ds], 0, 0, 0);
        }
        __builtin_amdgcn_s_setprio(0);
      }
    }
    __syncthreads();  // all reads of cur done; vmcnt(0) drain makes buf cur^1 ready
  }
  // epilogue: combine l across halves once; q = i0+w*32+l31 per lane;
  // d = ds*32 + rg*8 + hi5*4 + (0..3)
  float ltot = l + __shfl_xor(l, 32);
  float invl = 1.0f / ltot;
  int q = i0 + w * 32 + l31;
  float* orow = out + ((size_t)(b * NC + hd * NEMB + (q >> 3))) * NPIX + (q & 7) * NEMB;
#pragma unroll
  for (int ds = 0; ds < 4; ds++)
#pragma unroll
    for (int rg = 0; rg < 4; rg++) {
      f32x4 v;
#pragma unroll
      for (int i = 0; i < 4; i++) v[i] = yacc[ds][rg * 4 + i] * invl;
      *(f32x4*)(orow + ds * 32 + rg * 8 + hi5 * 4) = v;
    }
}

extern "C" void kernel_launch(void* const* d_in, const int* in_sizes, int n_in,
                              void* d_out, int out_size, void* d_ws, size_t ws_size,
                              hipStream_t stream) {
  const float* x  = (const float*)d_in[0];
  const float* wq = (const float*)d_in[1];
  const float* qb = (const float*)d_in[2];
  const float* wk = (const float*)d_in[3];
  const float* kb = (const float*)d_in[4];
  const float* wv = (const float*)d_in[5];
  const float* vb = (const float*)d_in[6];
  const float* rh = (const float*)d_in[7];
  const float* rw = (const float*)d_in[8];
  float* out = (float*)d_out;
  char* ws = (char*)d_ws;
  // ws layout (bytes): xt 16,777,216 | wb 1,572,864 | Q 16,777,216 | K 16,777,216 | V 16,777,216
  unsigned short* xt = (unsigned short*)(ws);
  unsigned short* wb = (unsigned short*)(ws + 16777216);
  unsigned short* Q  = (unsigned short*)(ws + 18350080);
  unsigned short* K  = (unsigned short*)(ws + 35127296);
  unsigned short* V  = (unsigned short*)(ws + 51904512);
  k_prep_x<<<2048, 256, 0, stream>>>(x, xt);
  k_prep_w<<<dim3(64, 3), 256, 0, stream>>>(wq, wk, wv, wb);
  k_qkv<<<1536, 256, 0, stream>>>(wb, xt, qb, kb, vb, rh, rw, Q, K, V);
  k_attn<<<512, 256, 0, stream>>>(Q, K, V, out);
}

// Round 14
// 101.867 us; speedup vs baseline: 1.1672x; 1.0191x over previous
//
#include <hip/hip_runtime.h>
#include <hip/hip_bf16.h>
#include <cstdint>

#define NB 16
#define NC 512
#define NPIX 1024
#define NHEADS 4
#define NEMB 128

typedef short bf16x8 __attribute__((ext_vector_type(8)));
typedef float f32x4 __attribute__((ext_vector_type(4)));
typedef float f32x16 __attribute__((ext_vector_type(16)));
typedef unsigned short u16x4 __attribute__((ext_vector_type(4)));
typedef unsigned short u16x8 __attribute__((ext_vector_type(8)));

__device__ __forceinline__ unsigned short f2bf(float f) {
  union { float f; unsigned u; } c; c.f = f;
  return (unsigned short)((c.u + 0x7FFFu + ((c.u >> 16) & 1u)) >> 16);
}

__device__ __forceinline__ unsigned cvtpk_bf16(float lo, float hi) {
  unsigned r;
  asm("v_cvt_pk_bf16_f32 %0, %1, %2" : "=v"(r) : "v"(lo), "v"(hi));
  return r;
}

__device__ __forceinline__ void gload_lds16(const void* g, void* l) {
  __builtin_amdgcn_global_load_lds(
      (const __attribute__((address_space(1))) unsigned int*)g,
      (__attribute__((address_space(3))) unsigned int*)l, 16, 0, 0);
}

// ---------- merged prep: blocks 0..2047 transpose x -> xt; 2048..2303 convert w ----------
// x tile path: [B][C][N] f32 -> xt [B][N][C] bf16; write phase re-reads the LDS tile
// in output-row order so 16 consecutive lanes emit one contiguous 256B row segment
// (full 128B-line coverage; the old path wrote 64B half-lines per 8-lane group).
__global__ void k_prep(const float* __restrict__ x, unsigned short* __restrict__ xt,
                       const float* __restrict__ wq, const float* __restrict__ wk,
                       const float* __restrict__ wv, unsigned short* __restrict__ wb) {
  int bid = blockIdx.x;
  if (bid >= 2048) {
    // weight convert: 3 x 512x512 f32 -> bf16, grid-stride over 256 tail blocks
    int wbid = bid - 2048;
    for (int i = wbid * 256 + threadIdx.x; i < 3 * 65536; i += 256 * 256) {
      int p = i >> 16, idx = i & 65535;
      const float* src = p == 0 ? wq : (p == 1 ? wk : wv);
      float4 v = ((const float4*)src)[idx];
      u16x4 o = { f2bf(v.x), f2bf(v.y), f2bf(v.z), f2bf(v.w) };
      ((u16x4*)(wb + (size_t)p * NC * NC))[idx] = o;
    }
    return;
  }
  __shared__ float tile[4][32][33];
  int nt = bid & 31, ct4 = (bid >> 5) & 3, b = bid >> 7;
  int n0 = nt * 32, c0 = ct4 * 128;
  int t = threadIdx.x;
  int r = t >> 3, q = t & 7;
#pragma unroll
  for (int s = 0; s < 4; s++) {
    float4 v = *(const float4*)(x + ((size_t)(b * NC + c0 + s * 32 + r)) * NPIX + n0 + q * 4);
    tile[s][r][q * 4 + 0] = v.x; tile[s][r][q * 4 + 1] = v.y;
    tile[s][r][q * 4 + 2] = v.z; tile[s][r][q * 4 + 3] = v.w;
  }
  __syncthreads();
  // coalesced write-out: 2 passes x 16B/thread; 16 lanes cover 256B of one xt row
#pragma unroll
  for (int pass = 0; pass < 2; pass++) {
    int idx = pass * 256 + t;
    int n = idx >> 4;            // 0..31
    int c8 = (idx & 15) * 8;     // 0..120, one s-subtile each (c8&31 + 8 <= 32)
    int s = c8 >> 5, cl = c8 & 31;
    u16x8 o;
#pragma unroll
    for (int j = 0; j < 8; j++) o[j] = f2bf(tile[s][cl + j][n]);
    *(u16x8*)(xt + ((size_t)(b * NPIX + n0 + n)) * NC + c0 + c8) = o;
  }
}

// ---------- QKV projection GEMM (r9 layouts, LDS-restaged coalesced epilogue) ----------
// p==0: Q -> (acc+bias)*scale*log2e, [b][hd][n][e]  (exp2-domain)
// p==1: K -> acc+bias+rh+rw, tiles 16KB: elem(jl,e) at byte jl*256 + ((2e)^((jl&7)<<4))
// p==2: V -> acc+bias,       tiles 16KB: elem(d,jl) at byte d*128 + ((2jl)^((d&7)<<4))
__global__ __launch_bounds__(256, 3) void k_qkv(
    const unsigned short* __restrict__ wb, const unsigned short* __restrict__ xt,
    const float* __restrict__ qb, const float* __restrict__ kb, const float* __restrict__ vb,
    const float* __restrict__ rh, const float* __restrict__ rw,
    unsigned short* __restrict__ Qs, unsigned short* __restrict__ Kn,
    unsigned short* __restrict__ Vm) {
  __shared__ __align__(16) char smem[32768];
  unsigned short* Alds = (unsigned short*)smem;
  unsigned short* Blds = (unsigned short*)(smem + 16384);
  int bid = blockIdx.x;
  int nt = bid & 7, mt = (bid >> 3) & 3;
  int rest = bid >> 5;
  int p = rest % 3, b = rest / 3;
  int m0 = mt * 128, n0 = nt * 128;
  const unsigned short* A = wb + (size_t)p * NC * NC + (size_t)m0 * NC;
  const unsigned short* Bx = xt + (size_t)b * NPIX * NC + (size_t)n0 * NC;
  int t = threadIdx.x;
  int lane = t & 63, wid = t >> 6;
  int wm = (wid >> 1) * 64, wn = (wid & 1) * 64;
  f32x4 acc[4][4] = {};
  for (int k0 = 0; k0 < NC; k0 += 64) {
#pragma unroll
    for (int i = 0; i < 4; i++) {
      int idx = i * 256 + t;
      int row = idx >> 3, col = (idx & 7) * 8;
      gload_lds16(A + (size_t)row * NC + k0 + col, &Alds[idx * 8]);
    }
#pragma unroll
    for (int i = 0; i < 4; i++) {
      int idx = i * 256 + t;
      int row = idx >> 3, col = (idx & 7) * 8;
      gload_lds16(Bx + (size_t)row * NC + k0 + col, &Blds[idx * 8]);
    }
    __syncthreads();
#pragma unroll
    for (int ks = 0; ks < 2; ks++) {
      int kk = ks * 32 + ((lane >> 4) << 3);
      bf16x8 af[4], bfr[4];
#pragma unroll
      for (int f = 0; f < 4; f++)
        af[f] = *(const bf16x8*)&Alds[(wm + f * 16 + (lane & 15)) * 64 + kk];
#pragma unroll
      for (int f = 0; f < 4; f++)
        bfr[f] = *(const bf16x8*)&Blds[(wn + f * 16 + (lane & 15)) * 64 + kk];
#pragma unroll
      for (int fm = 0; fm < 4; fm++)
#pragma unroll
        for (int fn = 0; fn < 4; fn++)
          acc[fm][fn] = __builtin_amdgcn_mfma_f32_16x16x32_bf16(af[fm], bfr[fn], acc[fm][fn], 0, 0, 0);
    }
    __syncthreads();  // last iter: all LDS reads done -> safe to reuse smem below
  }
  // 512^-0.5 * log2(e): softmax runs in exp2 domain
  const float scale = 0.044194173824159216f * 1.4426950408889634f;
  // ---- build final-layout 32KB tile in LDS ----
  if (p == 2) {
#pragma unroll
    for (int fm = 0; fm < 4; fm++) {
#pragma unroll
      for (int r = 0; r < 4; r++) {
        int d = wm + fm * 16 + ((lane >> 4) << 2) + r;
        float bv = vb[m0 + d];
#pragma unroll
        for (int fn = 0; fn < 4; fn++) {
          int jloc = wn + fn * 16 + (lane & 15);
          int sub = jloc >> 6, jl = jloc & 63;
          *(unsigned short*)(smem + sub * 16384 + d * 128 + ((2 * jl) ^ ((d & 7) << 4))) =
              f2bf(acc[fm][fn][r] + bv);
        }
      }
    }
  } else if (p == 1) {
#pragma unroll
    for (int fm = 0; fm < 4; fm++) {
      int e0 = wm + fm * 16 + ((lane >> 4) << 2);
#pragma unroll
      for (int fn = 0; fn < 4; fn++) {
        int jloc = wn + fn * 16 + (lane & 15);
        int jg = n0 + jloc;
        int sub = jloc >> 6, jl = jloc & 63;
        u16x4 o;
#pragma unroll
        for (int r = 0; r < 4; r++) {
          float v = acc[fm][fn][r] + kb[m0 + e0 + r];
          v += rh[(m0 + e0 + r) * 32 + (jg & 31)] + rw[(m0 + e0 + r) * 32 + (jg >> 5)];
          o[r] = f2bf(v);
        }
        *(u16x4*)(smem + sub * 16384 + jl * 256 + ((2 * e0) ^ ((jl & 7) << 4))) = o;
      }
    }
  } else {
#pragma unroll
    for (int fm = 0; fm < 4; fm++) {
      int e0 = wm + fm * 16 + ((lane >> 4) << 2);
#pragma unroll
      for (int fn = 0; fn < 4; fn++) {
        int ncol = wn + fn * 16 + (lane & 15);
        u16x4 o;
#pragma unroll
        for (int r = 0; r < 4; r++)
          o[r] = f2bf((acc[fm][fn][r] + qb[m0 + e0 + r]) * scale);
        *(u16x4*)(smem + ncol * 256 + 2 * e0) = o;
      }
    }
  }
  __syncthreads();
  // ---- coalesced copy-out: 8 x 16B per thread ----
  char* gdst;
  if (p == 0)
    gdst = (char*)(Qs + ((size_t)((b * NHEADS + mt) * NPIX + n0)) * NEMB);
  else if (p == 1)
    gdst = (char*)(Kn + (size_t)(b * NHEADS + mt) * 131072 + (size_t)(n0 >> 6) * 8192);
  else
    gdst = (char*)(Vm + (size_t)(b * NHEADS + mt) * 131072 + (size_t)(n0 >> 6) * 8192);
#pragma unroll
  for (int i = 0; i < 8; i++)
    *(u16x8*)(gdst + i * 4096 + t * 16) = *(const u16x8*)(smem + i * 4096 + t * 16);
}

// ---------- flash attention (r9-proven): swapped QK^T (32x32 MFMA), in-register ----------
// exp2 softmax (no max — bounded logits), permlane pack, K/V pre-swizzled ->
// linear gload_lds staging, dbuf, 1 barrier/tile. grid = 512; 4 waves x 32 q-rows.
__global__ __launch_bounds__(256, 2) void k_attn(
    const unsigned short* __restrict__ Qs, const unsigned short* __restrict__ Kp,
    const unsigned short* __restrict__ Vp, float* __restrict__ out) {
  __shared__ __align__(16) char smem[65536];  // K dbuf 2x16KB @0, V dbuf 2x16KB @32768
  int bid = blockIdx.x;
  int pair = bid & 63;                        // b*4+hd; i-tiles of a pair share bid%8 -> XCD
  int b = pair >> 2, hd = pair & 3;
  int i0 = (bid >> 6) * 128;
  int t = threadIdx.x, w = t >> 6, lane = t & 63;
  int l31 = lane & 31, hi5 = lane >> 5;
  const unsigned short* Qb = Qs + (size_t)pair * NPIX * NEMB;
  const char* Kpb = (const char*)(Kp + (size_t)pair * 131072);
  const char* Vpb = (const char*)(Vp + (size_t)pair * 131072);

  // Q B-frags: lane holds Q[q = i0+w*32+l31][d8*16 + hi5*8 + e]
  bf16x8 qf[8];
  {
    const unsigned short* qr = Qb + (size_t)(i0 + w * 32 + l31) * NEMB + hi5 * 8;
#pragma unroll
    for (int d8 = 0; d8 < 8; d8++) qf[d8] = *(const bf16x8*)(qr + d8 * 16);
  }
  f32x16 yacc[4] = {};
  float l = 0.f;

  // prologue: stage tile 0 into buf 0
#pragma unroll
  for (int r = 0; r < 4; r++) {
    gload_lds16(Kpb + r * 4096 + t * 16, smem + r * 4096 + t * 16);
    gload_lds16(Vpb + r * 4096 + t * 16, smem + 32768 + r * 4096 + t * 16);
  }
  __syncthreads();

  for (int tt = 0; tt < 16; tt++) {
    int cur = tt & 1;
    if (tt < 15) {  // prefetch next tile into other buffer (drained by barrier at loop end)
      const char* kn = Kpb + (tt + 1) * 16384;
      const char* vn = Vpb + (tt + 1) * 16384;
      char* kd = smem + (cur ^ 1) * 16384;
      char* vd = smem + 32768 + (cur ^ 1) * 16384;
#pragma unroll
      for (int r = 0; r < 4; r++) {
        gload_lds16(kn + r * 4096 + t * 16, kd + r * 4096 + t * 16);
        gload_lds16(vn + r * 4096 + t * 16, vd + r * 4096 + t * 16);
      }
    }
    const char* Kl = smem + cur * 16384;
    const char* Vl = smem + 32768 + cur * 16384;
    // S^T = K Q^T : per lane, 32 S-values for q = l31 (k rows per C-layout)
    f32x16 sacc[2] = {};
    {
      int swz = (l31 & 7) << 4;
#pragma unroll
      for (int d8 = 0; d8 < 8; d8++) {
        int colb = (d8 * 32 + hi5 * 16) ^ swz;
        bf16x8 k0 = *(const bf16x8*)(Kl + l31 * 256 + colb);
        bf16x8 k1 = *(const bf16x8*)(Kl + (32 + l31) * 256 + colb);
        __builtin_amdgcn_s_setprio(1);
        sacc[0] = __builtin_amdgcn_mfma_f32_32x32x16_bf16(k0, qf[d8], sacc[0], 0, 0, 0);
        sacc[1] = __builtin_amdgcn_mfma_f32_32x32x16_bf16(k1, qf[d8], sacc[1], 0, 0, 0);
        __builtin_amdgcn_s_setprio(0);
      }
    }
    // P = exp2(S) directly (no max; bounded logits — r7 analysis); 4 independent
    // sum accumulators; l keeps own-half partial sums (combined in epilogue).
    float rs0 = 0.f, rs1 = 0.f, rs2 = 0.f, rs3 = 0.f;
#pragma unroll
    for (int c = 0; c < 2; c++)
#pragma unroll
      for (int i = 0; i < 16; i += 4) {
        float p0 = exp2f(sacc[c][i + 0]);
        float p1 = exp2f(sacc[c][i + 1]);
        float p2 = exp2f(sacc[c][i + 2]);
        float p3 = exp2f(sacc[c][i + 3]);
        sacc[c][i + 0] = p0; sacc[c][i + 1] = p1;
        sacc[c][i + 2] = p2; sacc[c][i + 3] = p3;
        rs0 += p0; rs1 += p1; rs2 += p2; rs3 += p3;
      }
    l += (rs0 + rs1) + (rs2 + rs3);
    // pack P to bf16 pairs, assemble PV B-frags via permlane32_swap (r9 algebra)
    unsigned up[2][4][2];
#pragma unroll
    for (int c = 0; c < 2; c++)
#pragma unroll
      for (int g = 0; g < 4; g++) {
        up[c][g][0] = cvtpk_bf16(sacc[c][4 * g + 0], sacc[c][4 * g + 1]);
        up[c][g][1] = cvtpk_bf16(sacc[c][4 * g + 2], sacc[c][4 * g + 3]);
      }
    bf16x8 pf[4];
#pragma unroll
    for (int c2 = 0; c2 < 4; c2++) {
      int c = c2 >> 1, gA = (c2 & 1) * 2, gB = gA + 1;
      unsigned a0 = up[c][gA][0], b0 = up[c][gB][0];
      unsigned a1 = up[c][gA][1], b1 = up[c][gB][1];
      asm("v_permlane32_swap_b32 %0, %1" : "+v"(a0), "+v"(b0));
      asm("v_permlane32_swap_b32 %0, %1" : "+v"(a1), "+v"(b1));
      unsigned wd[4] = { a0, a1, b0, b1 };
      pf[c2] = *(bf16x8*)wd;
    }
    // y^T += V^T P^T : A = V^T from LDS (16B contig), B = pf; C cols = q (= l31)
    {
      int swz = (l31 & 7) << 4;
#pragma unroll
      for (int c2 = 0; c2 < 4; c2++) {
        int colb = (c2 * 32 + hi5 * 16) ^ swz;
        __builtin_amdgcn_s_setprio(1);
#pragma unroll
        for (int ds = 0; ds < 4; ds++) {
          bf16x8 vf = *(const bf16x8*)(Vl + (ds * 32 + l31) * 128 + colb);
          yacc[ds] = __builtin_amdgcn_mfma_f32_32x32x16_bf16(vf, pf[c2], yacc[ds], 0, 0, 0);
        }
        __builtin_amdgcn_s_setprio(0);
      }
    }
    __syncthreads();  // all reads of cur done; vmcnt(0) drain makes buf cur^1 ready
  }
  // epilogue: combine l across halves once; q = i0+w*32+l31 per lane;
  // d = ds*32 + rg*8 + hi5*4 + (0..3)
  float ltot = l + __shfl_xor(l, 32);
  float invl = 1.0f / ltot;
  int q = i0 + w * 32 + l31;
  float* orow = out + ((size_t)(b * NC + hd * NEMB + (q >> 3))) * NPIX + (q & 7) * NEMB;
#pragma unroll
  for (int ds = 0; ds < 4; ds++)
#pragma unroll
    for (int rg = 0; rg < 4; rg++) {
      f32x4 v;
#pragma unroll
      for (int i = 0; i < 4; i++) v[i] = yacc[ds][rg * 4 + i] * invl;
      *(f32x4*)(orow + ds * 32 + rg * 8 + hi5 * 4) = v;
    }
}

extern "C" void kernel_launch(void* const* d_in, const int* in_sizes, int n_in,
                              void* d_out, int out_size, void* d_ws, size_t ws_size,
                              hipStream_t stream) {
  const float* x  = (const float*)d_in[0];
  const float* wq = (const float*)d_in[1];
  const float* qb = (const float*)d_in[2];
  const float* wk = (const float*)d_in[3];
  const float* kb = (const float*)d_in[4];
  const float* wv = (const float*)d_in[5];
  const float* vb = (const float*)d_in[6];
  const float* rh = (const float*)d_in[7];
  const float* rw = (const float*)d_in[8];
  float* out = (float*)d_out;
  char* ws = (char*)d_ws;
  // ws layout (bytes): xt 16,777,216 | wb 1,572,864 | Q 16,777,216 | K 16,777,216 | V 16,777,216
  unsigned short* xt = (unsigned short*)(ws);
  unsigned short* wb = (unsigned short*)(ws + 16777216);
  unsigned short* Q  = (unsigned short*)(ws + 18350080);
  unsigned short* K  = (unsigned short*)(ws + 35127296);
  unsigned short* V  = (unsigned short*)(ws + 51904512);
  k_prep<<<2304, 256, 0, stream>>>(x, xt, wq, wk, wv, wb);
  k_qkv<<<1536, 256, 0, stream>>>(wb, xt, qb, kb, vb, rh, rw, Q, K, V);
  k_attn<<<512, 256, 0, stream>>>(Q, K, V, out);
}